// Round 9
// baseline (130.836 us; speedup 1.0000x reference)
//
#include <hip/hip_runtime.h>
#include <math.h>

#define PI9 (2.0f * 3.14159265358979323846f / 9.0f)

typedef float f32x4 __attribute__((ext_vector_type(4)));
typedef unsigned short us8 __attribute__((ext_vector_type(8)));
typedef __bf16 bf16x8 __attribute__((ext_vector_type(8)));

__device__ __forceinline__ float ssp_f(float x) {
  const float ax = fabsf(x);
  const float t = __expf(-ax);
  return fmaxf(x, 0.f) + __logf(1.f + t) - 0.69314718f;
}

__device__ __forceinline__ unsigned short f2bf(float f) {
  unsigned int u = __float_as_uint(f);
  unsigned int r = (u + 0x7FFFu + ((u >> 16) & 1u)) >> 16;
  return (unsigned short)r;
}

__device__ __forceinline__ float bf2f(unsigned short u) {
  return __uint_as_float(((unsigned int)u) << 16);
}

// ===========================================================================
// prep_kernel roles: [0,nMlp) MLP(128 edges) | [+nScat) scatter |
//                    [+nXcvt) x->bf16 convert | [+9) precompute_C
// ===========================================================================
__device__ void mlp_body(
    int mblk, unsigned char* smem, const float* __restrict__ win,
    const float* __restrict__ W1, const float* __restrict__ W2,
    const float* __restrict__ W3, const float* __restrict__ a_w,
    const float* __restrict__ den, unsigned short* __restrict__ w48b) {
  float* W1s = (float*)smem;                              // 2048 B
  unsigned short* W2T = (unsigned short*)(smem + 2048);   // 8192 B
  unsigned short* W3T = (unsigned short*)(smem + 10240);  // 6144 B
  unsigned short* H1 = (unsigned short*)(smem + 16384);   // 8192 B
  unsigned short* H2 = (unsigned short*)(smem + 24576);   // 8192 B
  const int t = threadIdx.x;

  const float invden = 1.f / den[0];
  const float sc0 = a_w[0] * invden, sc1 = a_w[10] * invden, sc2 = a_w[22] * invden;
  const float rs8 = 0.35355339059327373f;

  if (t < 128) {
    float4 v = ((const float4*)W1)[t];
    v.x *= rs8; v.y *= rs8; v.z *= rs8; v.w *= rs8;
    ((float4*)W1s)[t] = v;
  }
  for (int i = t; i < 4096; i += 256) {
    const int k = i >> 6, j = i & 63;
    W2T[j * 64 + ((((k >> 3) ^ (j & 7)) << 3)) + (k & 7)] = f2bf(W2[i] * 0.125f);
  }
  for (int i = t; i < 3072; i += 256) {
    const int k = i / 48, j = i % 48;
    const int jm = j % 3;
    const float s = (jm == 0) ? sc0 : ((jm == 1) ? sc1 : sc2);
    W3T[j * 64 + ((((k >> 3) ^ (j & 7)) << 3)) + (k & 7)] = f2bf(W3[i] * 0.125f * s);
  }
  __syncthreads();

  const int w = t >> 6, l = t & 63;
  const int er = l & 15, g = l >> 4;
  unsigned short* h1p = H1 + w * 1024;
  unsigned short* h2p = H2 + w * 1024;

#pragma unroll 1
  for (int rep = 0; rep < 2; ++rep) {
    const int e = mblk * 128 + rep * 64 + w * 16 + er;

    float in8[8];
    {
      const float4 A = *(const float4*)(win + (size_t)e * 8);
      const float4 B = *(const float4*)(win + (size_t)e * 8 + 4);
      in8[0] = A.x; in8[1] = A.y; in8[2] = A.z; in8[3] = A.w;
      in8[4] = B.x; in8[5] = B.y; in8[6] = B.z; in8[7] = B.w;
    }
    float h[16];
#pragma unroll
    for (int c = 0; c < 16; ++c) h[c] = 0.f;
#pragma unroll
    for (int k = 0; k < 8; ++k) {
      const float* wr = &W1s[k * 64 + g * 16];
      const float4 w0 = *(const float4*)wr;
      const float4 w1 = *(const float4*)(wr + 4);
      const float4 w2 = *(const float4*)(wr + 8);
      const float4 w3 = *(const float4*)(wr + 12);
      const float ik = in8[k];
      h[0]  = fmaf(ik, w0.x, h[0]);  h[1]  = fmaf(ik, w0.y, h[1]);
      h[2]  = fmaf(ik, w0.z, h[2]);  h[3]  = fmaf(ik, w0.w, h[3]);
      h[4]  = fmaf(ik, w1.x, h[4]);  h[5]  = fmaf(ik, w1.y, h[5]);
      h[6]  = fmaf(ik, w1.z, h[6]);  h[7]  = fmaf(ik, w1.w, h[7]);
      h[8]  = fmaf(ik, w2.x, h[8]);  h[9]  = fmaf(ik, w2.y, h[9]);
      h[10] = fmaf(ik, w2.z, h[10]); h[11] = fmaf(ik, w2.w, h[11]);
      h[12] = fmaf(ik, w3.x, h[12]); h[13] = fmaf(ik, w3.y, h[13]);
      h[14] = fmaf(ik, w3.z, h[14]); h[15] = fmaf(ik, w3.w, h[15]);
    }
    us8 pk0, pk1;
#pragma unroll
    for (int jj = 0; jj < 8; ++jj) pk0[jj] = f2bf(ssp_f(h[jj]));
#pragma unroll
    for (int jj = 0; jj < 8; ++jj) pk1[jj] = f2bf(ssp_f(h[8 + jj]));
    *(us8*)&h1p[er * 64 + (((2 * g) ^ (er & 7)) << 3)] = pk0;
    *(us8*)&h1p[er * 64 + (((2 * g + 1) ^ (er & 7)) << 3)] = pk1;
    __builtin_amdgcn_wave_barrier();

    const us8 a0 = *(const us8*)&h1p[er * 64 + ((g ^ (er & 7)) << 3)];
    const us8 a1 = *(const us8*)&h1p[er * 64 + (((g + 4) ^ (er & 7)) << 3)];
    float hh[16];
#pragma unroll
    for (int nt = 0; nt < 4; ++nt) {
      const int j = nt * 16 + er;
      const us8 b0 = *(const us8*)&W2T[j * 64 + ((g ^ (j & 7)) << 3)];
      const us8 b1 = *(const us8*)&W2T[j * 64 + (((g + 4) ^ (j & 7)) << 3)];
      f32x4 acc = {0.f, 0.f, 0.f, 0.f};
      acc = __builtin_amdgcn_mfma_f32_16x16x32_bf16(
          __builtin_bit_cast(bf16x8, a0), __builtin_bit_cast(bf16x8, b0), acc, 0, 0, 0);
      acc = __builtin_amdgcn_mfma_f32_16x16x32_bf16(
          __builtin_bit_cast(bf16x8, a1), __builtin_bit_cast(bf16x8, b1), acc, 0, 0, 0);
#pragma unroll
      for (int r = 0; r < 4; ++r) hh[nt * 4 + r] = ssp_f(acc[r]);
    }
#pragma unroll
    for (int nt = 0; nt < 4; ++nt)
#pragma unroll
      for (int r = 0; r < 4; ++r) {
        const int e2 = g * 4 + r;
        const int k2 = nt * 16 + er;
        h2p[e2 * 64 + ((((k2 >> 3) ^ (e2 & 7)) << 3)) + (k2 & 7)] = f2bf(hh[nt * 4 + r]);
      }
    __builtin_amdgcn_wave_barrier();

    const us8 c0 = *(const us8*)&h2p[er * 64 + ((g ^ (er & 7)) << 3)];
    const us8 c1 = *(const us8*)&h2p[er * 64 + (((g + 4) ^ (er & 7)) << 3)];
    const int ebase = mblk * 128 + rep * 64 + w * 16 + g * 4;
#pragma unroll
    for (int nt = 0; nt < 3; ++nt) {
      const int o = nt * 16 + er;
      const us8 b0 = *(const us8*)&W3T[o * 64 + ((g ^ (o & 7)) << 3)];
      const us8 b1 = *(const us8*)&W3T[o * 64 + (((g + 4) ^ (o & 7)) << 3)];
      f32x4 acc = {0.f, 0.f, 0.f, 0.f};
      acc = __builtin_amdgcn_mfma_f32_16x16x32_bf16(
          __builtin_bit_cast(bf16x8, c0), __builtin_bit_cast(bf16x8, b0), acc, 0, 0, 0);
      acc = __builtin_amdgcn_mfma_f32_16x16x32_bf16(
          __builtin_bit_cast(bf16x8, c1), __builtin_bit_cast(bf16x8, b1), acc, 0, 0, 0);
#pragma unroll
      for (int r = 0; r < 4; ++r)
        w48b[(size_t)(ebase + r) * 48 + o] = f2bf(acc[r]);
    }
    __builtin_amdgcn_wave_barrier();
  }
}

__device__ void precompute_body(
    int d, unsigned char* smem,
    const float* __restrict__ Ux_re, const float* __restrict__ Ux_im,
    const float* __restrict__ Uf_re, const float* __restrict__ Uf_im,
    const float* __restrict__ Vo_re, const float* __restrict__ Vo_im,
    float* __restrict__ CT) {
  float* G = (float*)smem;
  float* TL = (float*)(smem + 5840);
  float* cs9 = (float*)(smem + 8768);
  float* sn9 = (float*)(smem + 8816);
  const int t0 = threadIdx.x;

  if (t0 < 9) {
    float s, c;
    __sincosf(PI9 * (float)t0, &s, &c);
    cs9[t0] = c; sn9[t0] = s;
  }
  __syncthreads();

  for (int t = t0; t < 1458; t += 256) {
    const int which = t / 729, idx = t % 729;
    const int p = idx / 81, ab = idx % 81, a = ab / 9, b = ab % 9;
    const float* Ure = which ? Uf_re : Ux_re;
    const float* Uim = which ? Uf_im : Ux_im;
    float g = 0.f;
#pragma unroll
    for (int v = 0; v < 3; ++v) {
      const int uc = v + 2;
      float hre = 0.f, him = 0.f;
#pragma unroll
      for (int ui = 0; ui < 5; ++ui) {
        const int u = (ui + 7) % 9;
        const float re = Ure[p * 25 + ui * 5 + uc];
        const float im = Uim[p * 25 + ui * 5 + uc];
        const int k = (u * a) % 9;
        const float c = cs9[k], s = sn9[k];
        hre += re * c - im * s;
        him += re * s + im * c;
      }
      hre *= (1.f / 9.f); him *= (1.f / 9.f);
      if (v == 0) {
        g += hre;
      } else {
        const int k = (v * b) % 9;
        g += 2.f * (hre * cs9[k] - him * sn9[k]);
      }
    }
    G[which * 729 + p * 81 + ab] = g * (1.f / 9.f);
  }
  __syncthreads();

  for (int t = t0; t < 729; t += 256) {
    const int ab = t / 9, dd = t % 9, a = ab / 9, b = ab % 9;
    float acc = 0.f;
    for (int u = 0; u < 9; ++u)
      for (int v = 0; v < 5; ++v) {
        const int k = (u * a + v * b) % 9;
        acc += Vo_re[u * 45 + v * 9 + dd] * cs9[k]
             + Vo_im[u * 45 + v * 9 + dd] * sn9[k];
      }
    TL[ab * 9 + dd] = acc;
  }
  __syncthreads();

  if (t0 < 108) {
    const int p = t0 / 12, q = t0 % 12;
    float acc = 0.f;
    if (q < 9) {
      for (int ab = 0; ab < 81; ++ab)
        acc += G[p * 81 + ab] * G[729 + q * 81 + ab] * TL[ab * 9 + d];
    }
    CT[(d * 9 + p) * 12 + q] = acc;
  }
}

__global__ __launch_bounds__(256) void prep_kernel(
    const float* __restrict__ win, const float* __restrict__ W1,
    const float* __restrict__ W2, const float* __restrict__ W3,
    const float* __restrict__ a_w, const float* __restrict__ den,
    unsigned short* __restrict__ w48b,
    const int* __restrict__ dst, const int* __restrict__ src, int E,
    int* __restrict__ cnt, int2* __restrict__ slots2,
    const float* __restrict__ xsrc, int NT, unsigned short* __restrict__ xbf,
    const float* __restrict__ Ux_re, const float* __restrict__ Ux_im,
    const float* __restrict__ Uf_re, const float* __restrict__ Uf_im,
    const float* __restrict__ Vo_re, const float* __restrict__ Vo_im,
    float* __restrict__ CT, int nMlp, int nScat, int nXcvt) {
  __shared__ __align__(16) unsigned char smem[32768];
  const int bid = blockIdx.x;
  if (bid < nMlp) {
    mlp_body(bid, smem, win, W1, W2, W3, a_w, den, w48b);
  } else if (bid < nMlp + nScat) {
    const int e = (bid - nMlp) * 256 + threadIdx.x;
    if (e < E) {
      const int d = dst[e];
      const int pos = atomicAdd(&cnt[d], 1);
      if (pos < 96) slots2[(size_t)d * 96 + pos] = make_int2(e, src[e]);
    }
  } else if (bid < nMlp + nScat + nXcvt) {
    const int base = (bid - nMlp - nScat) * 2048 + threadIdx.x * 8;
    if (base + 8 <= NT) {
      const float4 A = *(const float4*)(xsrc + base);
      const float4 B = *(const float4*)(xsrc + base + 4);
      us8 o;
      o[0] = f2bf(A.x); o[1] = f2bf(A.y); o[2] = f2bf(A.z); o[3] = f2bf(A.w);
      o[4] = f2bf(B.x); o[5] = f2bf(B.y); o[6] = f2bf(B.z); o[7] = f2bf(B.w);
      *(us8*)(xbf + base) = o;
    }
  } else {
    precompute_body(bid - nMlp - nScat - nXcvt, smem, Ux_re, Ux_im, Uf_re,
                    Uf_im, Vo_re, Vo_im, CT);
  }
}

// ===========================================================================
// Node kernel v8 (= R7 structure + bf16 x / bf16 w48): wave-per-node,
// 1-deep prefetch, uniform scalar loads for slots/filt, padded LDS.
// ===========================================================================
#define NLOADV(Fv, Xv, Wv0, Wv12, idx)                                       \
  {                                                                          \
    const int2 es_ = sl2[(idx)];                                             \
    const int e_ = __builtin_amdgcn_readfirstlane(es_.x);                    \
    const int s_ = __builtin_amdgcn_readfirstlane(es_.y);                    \
    _Pragma("unroll")                                                        \
    for (int q_ = 0; q_ < 9; ++q_) Fv[q_] = filt[(size_t)e_ * 9 + q_];       \
    if (l < 36) Xv = *(const ushort4*)(xbf + (size_t)s_ * 144 + l * 4);      \
    Wv0 = bf2f(w48b[(size_t)e_ * 48 + wc0]);                                 \
    Wv12 = bf2f(w48b[(size_t)e_ * 48 + wc12]);                               \
  }

#define NCOMPUTEV(Fv, Xv, Wv0, Wv12)                                         \
  {                                                                          \
    if (l < 36) {                                                            \
      xsl[w][wa0] = bf2f(Xv.x); xsl[w][wa1] = bf2f(Xv.y);                    \
      xsl[w][wa2] = bf2f(Xv.z); xsl[w][wa3] = bf2f(Xv.w);                    \
    }                                                                        \
    {                                                                        \
      float me = Fv[0] * C0a.x;                                              \
      me = fmaf(Fv[1], C0a.y, me); me = fmaf(Fv[2], C0a.z, me);              \
      me = fmaf(Fv[3], C0a.w, me); me = fmaf(Fv[4], C0b.x, me);              \
      me = fmaf(Fv[5], C0b.y, me); me = fmaf(Fv[6], C0b.z, me);              \
      me = fmaf(Fv[7], C0b.w, me); me = fmaf(Fv[8], C0c, me);                \
      MeT[w][me0] = me;                                                      \
    }                                                                        \
    if (l < 17) {                                                            \
      float me = Fv[0] * C1a.x;                                              \
      me = fmaf(Fv[1], C1a.y, me); me = fmaf(Fv[2], C1a.z, me);              \
      me = fmaf(Fv[3], C1a.w, me); me = fmaf(Fv[4], C1b.x, me);              \
      me = fmaf(Fv[5], C1b.y, me); me = fmaf(Fv[6], C1b.z, me);              \
      me = fmaf(Fv[7], C1b.w, me); me = fmaf(Fv[8], C1c, me);                \
      MeT[w][me1] = me;                                                      \
    }                                                                        \
    __builtin_amdgcn_wave_barrier();                                         \
    {                                                                        \
      const float* xr = &xsl[w][m * 12];                                     \
      const float4 x0 = *(const float4*)xr;                                  \
      const float4 x1 = *(const float4*)(xr + 4);                            \
      const float x8 = xr[8];                                                \
      const float* mr0 = &MeT[w][K * 12];                                    \
      const float4 ma = *(const float4*)mr0;                                 \
      const float4 mb = *(const float4*)(mr0 + 4);                           \
      float v = x0.x * ma.x + x0.y * ma.y + x0.z * ma.z + x0.w * ma.w        \
              + x1.x * mb.x + x1.y * mb.y + x1.z * mb.z + x1.w * mb.w        \
              + x8 * mr0[8];                                                 \
      a0 = fmaf(v, Wv0, a0);                                                 \
      const float* mr1 = &MeT[w][(K + 4) * 12];                              \
      const float4 mc = *(const float4*)mr1;                                 \
      const float4 md = *(const float4*)(mr1 + 4);                           \
      float v1 = x0.x * mc.x + x0.y * mc.y + x0.z * mc.z + x0.w * mc.w       \
               + x1.x * md.x + x1.y * md.y + x1.z * md.z + x1.w * md.w       \
               + x8 * mr1[8];                                                \
      a1 = fmaf(v1, Wv12, a1);                                               \
      if (K == 0) {                                                          \
        const float* mr2 = &MeT[w][96];                                      \
        const float4 mg = *(const float4*)mr2;                               \
        const float4 mh = *(const float4*)(mr2 + 4);                         \
        float v2 = x0.x * mg.x + x0.y * mg.y + x0.z * mg.z + x0.w * mg.w     \
                 + x1.x * mh.x + x1.y * mh.y + x1.z * mh.z + x1.w * mh.w     \
                 + x8 * mr2[8];                                              \
        a2v = fmaf(v2, Wv12, a2v);                                           \
      }                                                                      \
    }                                                                        \
    __builtin_amdgcn_wave_barrier();                                         \
  }

__global__ __launch_bounds__(256) void node_kernel(
    const unsigned short* __restrict__ xbf, const float* __restrict__ filt,
    const int* __restrict__ cnt, const int2* __restrict__ slots2,
    const unsigned short* __restrict__ w48b, const float* __restrict__ CT,
    float* __restrict__ out, int N, int totWaves) {
  __shared__ __align__(16) float xsl[4][16 * 12];
  __shared__ __align__(16) float MeT[4][9 * 12];
  __shared__ __align__(16) float osl[4][144];
  const int t = threadIdx.x, w = t >> 6, l = t & 63;

  const int m = l & 15, K = l >> 4;
  const int wc0 = m * 3 + ((K == 0) ? 0 : 1);
  const int wc12 = m * 3 + 2;
  const int dd0 = l / 9, p0 = l % 9;
  const int dd1 = (l + 64) / 9, p1 = (l + 64) % 9;
  const int me0 = dd0 * 12 + p0;
  const int me1 = dd1 * 12 + p1;

  int wa0, wa1, wa2, wa3;
  {
    const int j0 = l * 4;
    wa0 = (j0 / 9) * 12 + (j0 % 9);
    wa1 = ((j0 + 1) / 9) * 12 + ((j0 + 1) % 9);
    wa2 = ((j0 + 2) / 9) * 12 + ((j0 + 2) % 9);
    wa3 = ((j0 + 3) / 9) * 12 + ((j0 + 3) % 9);
  }

  const float* c0p = CT + (dd0 * 9 + p0) * 12;
  const float4 C0a = *(const float4*)c0p;
  const float4 C0b = *(const float4*)(c0p + 4);
  const float  C0c = c0p[8];
  const float* c1p = CT + ((l < 17) ? (dd1 * 9 + p1) * 12 : 0);
  const float4 C1a = *(const float4*)c1p;
  const float4 C1b = *(const float4*)(c1p + 4);
  const float  C1c = c1p[8];

  const int waveId = blockIdx.x * 4 + w;

  for (int n = waveId; n < N; n += totWaves) {
    int deg = cnt[n];
    if (deg > 96) deg = 96;
    const int2* sl2 = slots2 + (size_t)n * 96;

    float a0 = 0.f, a1 = 0.f, a2v = 0.f;

    if (deg > 0) {
      float Af[9], Bf[9];
      ushort4 Ax = make_ushort4(0, 0, 0, 0);
      ushort4 Bx = make_ushort4(0, 0, 0, 0);
      float Aw0, Aw12, Bw0, Bw12;

      NLOADV(Af, Ax, Aw0, Aw12, 0);
      int i = 0;
      while (true) {
        if (i + 1 < deg) NLOADV(Bf, Bx, Bw0, Bw12, i + 1);
        NCOMPUTEV(Af, Ax, Aw0, Aw12);
        ++i;
        if (i >= deg) break;
        if (i + 1 < deg) NLOADV(Af, Ax, Aw0, Aw12, i + 1);
        NCOMPUTEV(Bf, Bx, Bw0, Bw12);
        ++i;
        if (i >= deg) break;
      }
    }

    osl[w][m * 9 + K] = a0;
    osl[w][m * 9 + K + 4] = a1;
    if (K == 0) osl[w][m * 9 + 8] = a2v;
    __builtin_amdgcn_wave_barrier();
    if (l < 36)
      *(float4*)(out + (size_t)n * 144 + l * 4) = *(const float4*)&osl[w][l * 4];
    __builtin_amdgcn_wave_barrier();
  }
}

// ---------------------------------------------------------------------------
extern "C" void kernel_launch(void* const* d_in, const int* in_sizes, int n_in,
                              void* d_out, int out_size, void* d_ws, size_t ws_size,
                              hipStream_t stream) {
  const float* x      = (const float*)d_in[0];
  const float* filt   = (const float*)d_in[1];
  const float* win    = (const float*)d_in[2];
  const int*   eidx   = (const int*)d_in[3];
  const float* Ux_re  = (const float*)d_in[4];
  const float* Ux_im  = (const float*)d_in[5];
  const float* Uf_re  = (const float*)d_in[6];
  const float* Uf_im  = (const float*)d_in[7];
  const float* Vo_re  = (const float*)d_in[8];
  const float* Vo_im  = (const float*)d_in[9];
  const float* W1     = (const float*)d_in[10];
  const float* W2     = (const float*)d_in[11];
  const float* W3     = (const float*)d_in[12];
  const float* a_w    = (const float*)d_in[13];
  const float* den    = (const float*)d_in[14];
  float* out = (float*)d_out;

  const int N = in_sizes[0] / 144;          // 10000
  const int E = in_sizes[3] / 2;            // 160000
  const int NT = N * 144;
  const int* dst = eidx;
  const int* src = eidx + E;

  char* wsb = (char*)d_ws;
  const size_t off_cnt  = 8192;
  const size_t off_slot = off_cnt + 40960;
  const size_t off_w48  = off_slot + (size_t)N * 96 * 8;
  const size_t off_xbf  = off_w48 + (size_t)E * 48 * 2;

  float*          CT    = (float*)wsb;
  int*            cnt   = (int*)(wsb + off_cnt);
  int2*           slot2 = (int2*)(wsb + off_slot);
  unsigned short* w48b  = (unsigned short*)(wsb + off_w48);
  unsigned short* xbf   = (unsigned short*)(wsb + off_xbf);

  const int nMlp = E / 128;                    // 1250
  const int nScat = (E + 255) / 256;           // 625
  const int nXcvt = (NT + 2047) / 2048;        // 704

  hipMemsetAsync(cnt, 0, (size_t)N * sizeof(int), stream);
  prep_kernel<<<nMlp + nScat + nXcvt + 9, 256, 0, stream>>>(
      win, W1, W2, W3, a_w, den, w48b,
      dst, src, E, cnt, slot2,
      x, NT, xbf,
      Ux_re, Ux_im, Uf_re, Uf_im, Vo_re, Vo_im, CT, nMlp, nScat, nXcvt);

  const int nodeBlocks = (N + 3) / 4;          // 1 node per wave
  node_kernel<<<nodeBlocks, 256, 0, stream>>>(
      xbf, filt, cnt, slot2, w48b, CT, out, N, nodeBlocks * 4);
}

// Round 10
// 112.977 us; speedup vs baseline: 1.1581x; 1.1581x over previous
//
#include <hip/hip_runtime.h>
#include <math.h>

#define PI9 (2.0f * 3.14159265358979323846f / 9.0f)

typedef float f32x4 __attribute__((ext_vector_type(4)));
typedef unsigned short us8 __attribute__((ext_vector_type(8)));
typedef __bf16 bf16x8 __attribute__((ext_vector_type(8)));
typedef unsigned int u32x4 __attribute__((ext_vector_type(4)));

__device__ __forceinline__ float ssp_f(float x) {
  const float ax = fabsf(x);
  const float t = __expf(-ax);
  return fmaxf(x, 0.f) + __logf(1.f + t) - 0.69314718f;
}

__device__ __forceinline__ unsigned short f2bf(float f) {
  unsigned int u = __float_as_uint(f);
  unsigned int r = (u + 0x7FFFu + ((u >> 16) & 1u)) >> 16;
  return (unsigned short)r;
}

// ===========================================================================
// precompute_C body (9 blocks, one d-slice each) -> CT[d][p][q pad 12]
// ===========================================================================
__device__ void precompute_body(
    int d, unsigned char* smem,
    const float* __restrict__ Ux_re, const float* __restrict__ Ux_im,
    const float* __restrict__ Uf_re, const float* __restrict__ Uf_im,
    const float* __restrict__ Vo_re, const float* __restrict__ Vo_im,
    float* __restrict__ CT) {
  float* G = (float*)smem;                // 2*729 f
  float* TL = (float*)(smem + 5840);      // 729 f
  float* cs9 = (float*)(smem + 8768);
  float* sn9 = (float*)(smem + 8816);
  const int t0 = threadIdx.x;

  if (t0 < 9) {
    float s, c;
    __sincosf(PI9 * (float)t0, &s, &c);
    cs9[t0] = c; sn9[t0] = s;
  }
  __syncthreads();

  for (int t = t0; t < 1458; t += 256) {
    const int which = t / 729, idx = t % 729;
    const int p = idx / 81, ab = idx % 81, a = ab / 9, b = ab % 9;
    const float* Ure = which ? Uf_re : Ux_re;
    const float* Uim = which ? Uf_im : Ux_im;
    float g = 0.f;
#pragma unroll
    for (int v = 0; v < 3; ++v) {
      const int uc = v + 2;
      float hre = 0.f, him = 0.f;
#pragma unroll
      for (int ui = 0; ui < 5; ++ui) {
        const int u = (ui + 7) % 9;
        const float re = Ure[p * 25 + ui * 5 + uc];
        const float im = Uim[p * 25 + ui * 5 + uc];
        const int k = (u * a) % 9;
        const float c = cs9[k], s = sn9[k];
        hre += re * c - im * s;
        him += re * s + im * c;
      }
      hre *= (1.f / 9.f); him *= (1.f / 9.f);
      if (v == 0) {
        g += hre;
      } else {
        const int k = (v * b) % 9;
        g += 2.f * (hre * cs9[k] - him * sn9[k]);
      }
    }
    G[which * 729 + p * 81 + ab] = g * (1.f / 9.f);
  }
  __syncthreads();

  for (int t = t0; t < 729; t += 256) {
    const int ab = t / 9, dd = t % 9, a = ab / 9, b = ab % 9;
    float acc = 0.f;
    for (int u = 0; u < 9; ++u)
      for (int v = 0; v < 5; ++v) {
        const int k = (u * a + v * b) % 9;
        acc += Vo_re[u * 45 + v * 9 + dd] * cs9[k]
             + Vo_im[u * 45 + v * 9 + dd] * sn9[k];
      }
    TL[ab * 9 + dd] = acc;
  }
  __syncthreads();

  if (t0 < 108) {
    const int p = t0 / 12, q = t0 % 12;
    float acc = 0.f;
    if (q < 9) {
      for (int ab = 0; ab < 81; ++ab)
        acc += G[p * 81 + ab] * G[729 + q * 81 + ab] * TL[ab * 9 + d];
    }
    CT[(d * 9 + p) * 12 + q] = acc;
  }
}

// ===========================================================================
// prep1: [0,nScat) scatter (packed int2 {e,src}) | [+9) precompute_C
// ===========================================================================
__global__ __launch_bounds__(256) void prep1_kernel(
    const int* __restrict__ dst, const int* __restrict__ src, int E,
    int* __restrict__ cnt, int2* __restrict__ slots2,
    const float* __restrict__ Ux_re, const float* __restrict__ Ux_im,
    const float* __restrict__ Uf_re, const float* __restrict__ Uf_im,
    const float* __restrict__ Vo_re, const float* __restrict__ Vo_im,
    float* __restrict__ CT, int nScat) {
  __shared__ __align__(16) unsigned char smem[9216];
  const int bid = blockIdx.x;
  if (bid < nScat) {
    const int e = bid * 256 + threadIdx.x;
    if (e < E) {
      const int d = dst[e];
      const int pos = atomicAdd(&cnt[d], 1);
      if (pos < 96) slots2[(size_t)d * 96 + pos] = make_int2(e, src[e]);
    }
  } else {
    precompute_body(bid - nScat, smem, Ux_re, Ux_im, Uf_re, Uf_im,
                    Vo_re, Vo_im, CT);
  }
}

// ===========================================================================
// MLP body (4 reps = 256 edges / block), w48 f32 output
// ===========================================================================
__device__ void mlp_body(
    int mblk, unsigned char* smem, const float* __restrict__ win,
    const float* __restrict__ W1, const float* __restrict__ W2,
    const float* __restrict__ W3, const float* __restrict__ a_w,
    const float* __restrict__ den, float* __restrict__ w48) {
  float* W1s = (float*)smem;                              // 2048 B
  unsigned short* W2T = (unsigned short*)(smem + 2048);   // 8192 B
  unsigned short* W3T = (unsigned short*)(smem + 10240);  // 6144 B
  unsigned short* H1 = (unsigned short*)(smem + 16384);   // 8192 B
  unsigned short* H2 = (unsigned short*)(smem + 24576);   // 8192 B
  const int t = threadIdx.x;

  const float invden = 1.f / den[0];
  const float sc0 = a_w[0] * invden, sc1 = a_w[10] * invden, sc2 = a_w[22] * invden;
  const float rs8 = 0.35355339059327373f;

  if (t < 128) {
    float4 v = ((const float4*)W1)[t];
    v.x *= rs8; v.y *= rs8; v.z *= rs8; v.w *= rs8;
    ((float4*)W1s)[t] = v;
  }
  for (int i = t; i < 4096; i += 256) {
    const int k = i >> 6, j = i & 63;
    W2T[j * 64 + ((((k >> 3) ^ (j & 7)) << 3)) + (k & 7)] = f2bf(W2[i] * 0.125f);
  }
  for (int i = t; i < 3072; i += 256) {
    const int k = i / 48, j = i % 48;
    const int jm = j % 3;
    const float s = (jm == 0) ? sc0 : ((jm == 1) ? sc1 : sc2);
    W3T[j * 64 + ((((k >> 3) ^ (j & 7)) << 3)) + (k & 7)] = f2bf(W3[i] * 0.125f * s);
  }
  __syncthreads();

  const int w = t >> 6, l = t & 63;
  const int er = l & 15, g = l >> 4;
  unsigned short* h1p = H1 + w * 1024;
  unsigned short* h2p = H2 + w * 1024;

#pragma unroll 1
  for (int rep = 0; rep < 4; ++rep) {
    const int e = mblk * 256 + rep * 64 + w * 16 + er;

    float in8[8];
    {
      const float4 A = *(const float4*)(win + (size_t)e * 8);
      const float4 B = *(const float4*)(win + (size_t)e * 8 + 4);
      in8[0] = A.x; in8[1] = A.y; in8[2] = A.z; in8[3] = A.w;
      in8[4] = B.x; in8[5] = B.y; in8[6] = B.z; in8[7] = B.w;
    }
    float h[16];
#pragma unroll
    for (int c = 0; c < 16; ++c) h[c] = 0.f;
#pragma unroll
    for (int k = 0; k < 8; ++k) {
      const float* wr = &W1s[k * 64 + g * 16];
      const float4 w0 = *(const float4*)wr;
      const float4 w1 = *(const float4*)(wr + 4);
      const float4 w2 = *(const float4*)(wr + 8);
      const float4 w3 = *(const float4*)(wr + 12);
      const float ik = in8[k];
      h[0]  = fmaf(ik, w0.x, h[0]);  h[1]  = fmaf(ik, w0.y, h[1]);
      h[2]  = fmaf(ik, w0.z, h[2]);  h[3]  = fmaf(ik, w0.w, h[3]);
      h[4]  = fmaf(ik, w1.x, h[4]);  h[5]  = fmaf(ik, w1.y, h[5]);
      h[6]  = fmaf(ik, w1.z, h[6]);  h[7]  = fmaf(ik, w1.w, h[7]);
      h[8]  = fmaf(ik, w2.x, h[8]);  h[9]  = fmaf(ik, w2.y, h[9]);
      h[10] = fmaf(ik, w2.z, h[10]); h[11] = fmaf(ik, w2.w, h[11]);
      h[12] = fmaf(ik, w3.x, h[12]); h[13] = fmaf(ik, w3.y, h[13]);
      h[14] = fmaf(ik, w3.z, h[14]); h[15] = fmaf(ik, w3.w, h[15]);
    }
    us8 pk0, pk1;
#pragma unroll
    for (int jj = 0; jj < 8; ++jj) pk0[jj] = f2bf(ssp_f(h[jj]));
#pragma unroll
    for (int jj = 0; jj < 8; ++jj) pk1[jj] = f2bf(ssp_f(h[8 + jj]));
    *(us8*)&h1p[er * 64 + (((2 * g) ^ (er & 7)) << 3)] = pk0;
    *(us8*)&h1p[er * 64 + (((2 * g + 1) ^ (er & 7)) << 3)] = pk1;
    __builtin_amdgcn_wave_barrier();

    const us8 a0 = *(const us8*)&h1p[er * 64 + ((g ^ (er & 7)) << 3)];
    const us8 a1 = *(const us8*)&h1p[er * 64 + (((g + 4) ^ (er & 7)) << 3)];
    float hh[16];
#pragma unroll
    for (int nt = 0; nt < 4; ++nt) {
      const int j = nt * 16 + er;
      const us8 b0 = *(const us8*)&W2T[j * 64 + ((g ^ (j & 7)) << 3)];
      const us8 b1 = *(const us8*)&W2T[j * 64 + (((g + 4) ^ (j & 7)) << 3)];
      f32x4 acc = {0.f, 0.f, 0.f, 0.f};
      acc = __builtin_amdgcn_mfma_f32_16x16x32_bf16(
          __builtin_bit_cast(bf16x8, a0), __builtin_bit_cast(bf16x8, b0), acc, 0, 0, 0);
      acc = __builtin_amdgcn_mfma_f32_16x16x32_bf16(
          __builtin_bit_cast(bf16x8, a1), __builtin_bit_cast(bf16x8, b1), acc, 0, 0, 0);
#pragma unroll
      for (int r = 0; r < 4; ++r) hh[nt * 4 + r] = ssp_f(acc[r]);
    }
#pragma unroll
    for (int nt = 0; nt < 4; ++nt)
#pragma unroll
      for (int r = 0; r < 4; ++r) {
        const int e2 = g * 4 + r;
        const int k2 = nt * 16 + er;
        h2p[e2 * 64 + ((((k2 >> 3) ^ (e2 & 7)) << 3)) + (k2 & 7)] = f2bf(hh[nt * 4 + r]);
      }
    __builtin_amdgcn_wave_barrier();

    const us8 c0 = *(const us8*)&h2p[er * 64 + ((g ^ (er & 7)) << 3)];
    const us8 c1 = *(const us8*)&h2p[er * 64 + (((g + 4) ^ (er & 7)) << 3)];
    const int ebase = mblk * 256 + rep * 64 + w * 16 + g * 4;
#pragma unroll
    for (int nt = 0; nt < 3; ++nt) {
      const int o = nt * 16 + er;
      const us8 b0 = *(const us8*)&W3T[o * 64 + ((g ^ (o & 7)) << 3)];
      const us8 b1 = *(const us8*)&W3T[o * 64 + (((g + 4) ^ (o & 7)) << 3)];
      f32x4 acc = {0.f, 0.f, 0.f, 0.f};
      acc = __builtin_amdgcn_mfma_f32_16x16x32_bf16(
          __builtin_bit_cast(bf16x8, c0), __builtin_bit_cast(bf16x8, b0), acc, 0, 0, 0);
      acc = __builtin_amdgcn_mfma_f32_16x16x32_bf16(
          __builtin_bit_cast(bf16x8, c1), __builtin_bit_cast(bf16x8, b1), acc, 0, 0, 0);
#pragma unroll
      for (int r = 0; r < 4; ++r)
        w48[(size_t)(ebase + r) * 48 + o] = acc[r];
    }
    __builtin_amdgcn_wave_barrier();
  }
}

// ===========================================================================
// Me body: per edge, Me_T[d][p] = sum_q f[q]*C[p,q,d], bf16 rows of 5 dwords.
// 16 threads/edge (9 active: one per d-row).
// ===========================================================================
__device__ void me_body(int blk, unsigned char* smem,
                        const float* __restrict__ filt,
                        const float* __restrict__ CT,
                        unsigned int* __restrict__ meT, int E) {
  float* CTs = (float*)smem;   // 972 floats
  const int t = threadIdx.x;
  for (int i = t; i < 972; i += 256) CTs[i] = CT[i];
  __syncthreads();

  const int e = blk * 16 + (t >> 4);
  const int d = t & 15;
  if (d < 9 && e < E) {
    const float* fp = filt + (size_t)e * 9;
    const float f0 = fp[0], f1 = fp[1], f2 = fp[2], f3 = fp[3], f4 = fp[4];
    const float f5 = fp[5], f6 = fp[6], f7 = fp[7], f8 = fp[8];
    float me[9];
#pragma unroll
    for (int p = 0; p < 9; ++p) {
      const float* c = &CTs[(d * 9 + p) * 12];
      me[p] = f0 * c[0] + f1 * c[1] + f2 * c[2] + f3 * c[3] + f4 * c[4]
            + f5 * c[5] + f6 * c[6] + f7 * c[7] + f8 * c[8];
    }
    unsigned int* op = meT + ((size_t)e * 9 + d) * 5;
    op[0] = (unsigned)f2bf(me[0]) | ((unsigned)f2bf(me[1]) << 16);
    op[1] = (unsigned)f2bf(me[2]) | ((unsigned)f2bf(me[3]) << 16);
    op[2] = (unsigned)f2bf(me[4]) | ((unsigned)f2bf(me[5]) << 16);
    op[3] = (unsigned)f2bf(me[6]) | ((unsigned)f2bf(me[7]) << 16);
    op[4] = (unsigned)f2bf(me[8]);
  }
}

__global__ __launch_bounds__(256) void prep2_kernel(
    const float* __restrict__ win, const float* __restrict__ W1,
    const float* __restrict__ W2, const float* __restrict__ W3,
    const float* __restrict__ a_w, const float* __restrict__ den,
    float* __restrict__ w48, const float* __restrict__ filt,
    const float* __restrict__ CT, unsigned int* __restrict__ meT,
    int E, int nMlp) {
  __shared__ __align__(16) unsigned char smem[32768];
  const int bid = blockIdx.x;
  if (bid < nMlp) {
    mlp_body(bid, smem, win, W1, W2, W3, a_w, den, w48);
  } else {
    me_body(bid - nMlp, smem, filt, CT, meT, E);
  }
}

// ===========================================================================
// Node kernel v9: one MFMA per edge.  k=(l3,p) packing (27 of K=32):
//   A[m,k] = x[src][m,p] * w48[e][m*3+l3]   (lane: m=l&15, k-group g=l>>4)
//   B[k,d] = Me_e[p,d] * [l3 == l(d)]       (lane: d=l&15)
//   acc = mfma(A,B,acc) accumulates out[n][m][d] over edges.
// No LDS / no barriers in the edge loop; 4 waves/node (edge i = w mod 4).
// ===========================================================================
__global__ __launch_bounds__(256) void node_kernel(
    const float* __restrict__ x, const int* __restrict__ cnt,
    const int2* __restrict__ slots2, const float* __restrict__ w48,
    const unsigned int* __restrict__ meT, float* __restrict__ out, int N) {
  __shared__ __align__(16) float part[3][64][4];
  const int t = threadIdx.x, w = t >> 6, l = t & 63;
  const int n16 = l & 15, g = l >> 4;
  const int Ld = (n16 == 0) ? 0 : ((n16 < 4) ? 1 : 2);
  const bool dok = n16 < 9;
  const int drow = dok ? n16 : 0;
  const int n = blockIdx.x;

  int deg = cnt[n];
  if (deg > 96) deg = 96;
  const int2* sl2 = slots2 + (size_t)n * 96;

  f32x4 acc = {0.f, 0.f, 0.f, 0.f};

  for (int i = w; i < deg; i += 4) {
    const int2 es = sl2[i];
    const int e = __builtin_amdgcn_readfirstlane(es.x);
    const int s = __builtin_amdgcn_readfirstlane(es.y);

    const float* xr = x + (size_t)s * 144 + n16 * 9;
    const float4 xa = *(const float4*)xr;
    const float4 xb = *(const float4*)(xr + 4);
    const float x8v = xr[8];

    const float* wp = w48 + (size_t)e * 48 + n16 * 3;
    const float w0 = wp[0], w1 = wp[1], w2 = wp[2];

    const unsigned int* mrp = meT + ((size_t)e * 9 + drow) * 5;
    const unsigned int md0 = mrp[0], md1 = mrp[1], md2 = mrp[2];
    const unsigned int md3 = mrp[3], md4 = mrp[4];

    bf16x8 A;
    unsigned int B0, B1, B2, B3;
    if (g == 0) {
      // k0-7: l3=0, p=0..7
      A[0] = (__bf16)(xa.x * w0); A[1] = (__bf16)(xa.y * w0);
      A[2] = (__bf16)(xa.z * w0); A[3] = (__bf16)(xa.w * w0);
      A[4] = (__bf16)(xb.x * w0); A[5] = (__bf16)(xb.y * w0);
      A[6] = (__bf16)(xb.z * w0); A[7] = (__bf16)(xb.w * w0);
      const bool s0 = (Ld == 0);
      B0 = s0 ? md0 : 0u; B1 = s0 ? md1 : 0u;
      B2 = s0 ? md2 : 0u; B3 = s0 ? md3 : 0u;
    } else if (g == 1) {
      // k8: (0,p8); k9-15: (1, p0..6)
      A[0] = (__bf16)(x8v * w0);  A[1] = (__bf16)(xa.x * w1);
      A[2] = (__bf16)(xa.y * w1); A[3] = (__bf16)(xa.z * w1);
      A[4] = (__bf16)(xa.w * w1); A[5] = (__bf16)(xb.x * w1);
      A[6] = (__bf16)(xb.y * w1); A[7] = (__bf16)(xb.z * w1);
      const bool s0 = (Ld == 0), s1 = (Ld == 1);
      B0 = (s0 ? (md4 & 0xffffu) : 0u) | (s1 ? (md0 << 16) : 0u);
      B1 = s1 ? ((md0 >> 16) | (md1 << 16)) : 0u;   // me1,me2
      B2 = s1 ? ((md1 >> 16) | (md2 << 16)) : 0u;   // me3,me4
      B3 = s1 ? ((md2 >> 16) | (md3 << 16)) : 0u;   // me5,me6
    } else if (g == 2) {
      // k16,17: (1, p7,p8); k18-23: (2, p0..5)
      A[0] = (__bf16)(xb.w * w1); A[1] = (__bf16)(x8v * w1);
      A[2] = (__bf16)(xa.x * w2); A[3] = (__bf16)(xa.y * w2);
      A[4] = (__bf16)(xa.z * w2); A[5] = (__bf16)(xa.w * w2);
      A[6] = (__bf16)(xb.x * w2); A[7] = (__bf16)(xb.y * w2);
      const bool s1 = (Ld == 1), s2 = (Ld == 2);
      B0 = s1 ? ((md3 >> 16) | (md4 << 16)) : 0u;   // me7,me8
      B1 = s2 ? md0 : 0u; B2 = s2 ? md1 : 0u; B3 = s2 ? md2 : 0u;
    } else {
      // k24-26: (2, p6,p7,p8); k27-31 zero
      A[0] = (__bf16)(xb.z * w2); A[1] = (__bf16)(xb.w * w2);
      A[2] = (__bf16)(x8v * w2);
      A[3] = (__bf16)0.f; A[4] = (__bf16)0.f; A[5] = (__bf16)0.f;
      A[6] = (__bf16)0.f; A[7] = (__bf16)0.f;
      const bool s2 = (Ld == 2);
      B0 = s2 ? md3 : 0u;                            // me6,me7
      B1 = s2 ? (md4 & 0xffffu) : 0u;                // me8,0
      B2 = 0u; B3 = 0u;
    }
    u32x4 bv = {B0, B1, B2, B3};
    acc = __builtin_amdgcn_mfma_f32_16x16x32_bf16(
        A, __builtin_bit_cast(bf16x8, bv), acc, 0, 0, 0);
  }

  if (w > 0) {
#pragma unroll
    for (int r = 0; r < 4; ++r) part[w - 1][l][r] = acc[r];
  }
  __syncthreads();
  if (w == 0 && dok) {
    // C layout: col d = lane&15, row m = g*4 + r
    float* op = out + (size_t)n * 144 + (g * 4) * 9 + n16;
    op[0]  = acc[0] + part[0][l][0] + part[1][l][0] + part[2][l][0];
    op[9]  = acc[1] + part[0][l][1] + part[1][l][1] + part[2][l][1];
    op[18] = acc[2] + part[0][l][2] + part[1][l][2] + part[2][l][2];
    op[27] = acc[3] + part[0][l][3] + part[1][l][3] + part[2][l][3];
  }
}

// ---------------------------------------------------------------------------
extern "C" void kernel_launch(void* const* d_in, const int* in_sizes, int n_in,
                              void* d_out, int out_size, void* d_ws, size_t ws_size,
                              hipStream_t stream) {
  const float* x      = (const float*)d_in[0];
  const float* filt   = (const float*)d_in[1];
  const float* win    = (const float*)d_in[2];
  const int*   eidx   = (const int*)d_in[3];
  const float* Ux_re  = (const float*)d_in[4];
  const float* Ux_im  = (const float*)d_in[5];
  const float* Uf_re  = (const float*)d_in[6];
  const float* Uf_im  = (const float*)d_in[7];
  const float* Vo_re  = (const float*)d_in[8];
  const float* Vo_im  = (const float*)d_in[9];
  const float* W1     = (const float*)d_in[10];
  const float* W2     = (const float*)d_in[11];
  const float* W3     = (const float*)d_in[12];
  const float* a_w    = (const float*)d_in[13];
  const float* den    = (const float*)d_in[14];
  float* out = (float*)d_out;

  const int N = in_sizes[0] / 144;          // 10000
  const int E = in_sizes[3] / 2;            // 160000
  const int* dst = eidx;
  const int* src = eidx + E;

  char* wsb = (char*)d_ws;
  const size_t off_cnt  = 8192;
  const size_t off_slot = off_cnt + 40960;
  const size_t off_w48  = off_slot + (size_t)N * 96 * 8;
  const size_t off_me   = off_w48 + (size_t)E * 48 * 4;

  float*        CT    = (float*)wsb;
  int*          cnt   = (int*)(wsb + off_cnt);
  int2*         slot2 = (int2*)(wsb + off_slot);
  float*        w48   = (float*)(wsb + off_w48);
  unsigned int* meT   = (unsigned int*)(wsb + off_me);   // E*9*5 dwords

  const int nScat = (E + 255) / 256;        // 625
  const int nMlp  = E / 256;                // 625
  const int nMe   = (E + 15) / 16;          // 10000

  hipMemsetAsync(cnt, 0, (size_t)N * sizeof(int), stream);
  prep1_kernel<<<nScat + 9, 256, 0, stream>>>(
      dst, src, E, cnt, slot2,
      Ux_re, Ux_im, Uf_re, Uf_im, Vo_re, Vo_im, CT, nScat);
  prep2_kernel<<<nMlp + nMe, 256, 0, stream>>>(
      win, W1, W2, W3, a_w, den, w48, filt, CT, meT, E, nMlp);
  node_kernel<<<N, 256, 0, stream>>>(x, cnt, slot2, w48, meT, out, N);
}

// Round 11
// 103.999 us; speedup vs baseline: 1.2581x; 1.0863x over previous
//
#include <hip/hip_runtime.h>
#include <math.h>

#define PI9 (2.0f * 3.14159265358979323846f / 9.0f)

typedef float f32x4 __attribute__((ext_vector_type(4)));
typedef unsigned short us8 __attribute__((ext_vector_type(8)));
typedef __bf16 bf16x8 __attribute__((ext_vector_type(8)));
typedef unsigned int u32x4 __attribute__((ext_vector_type(4)));

__device__ __forceinline__ float ssp_f(float x) {
  const float ax = fabsf(x);
  const float t = __expf(-ax);
  return fmaxf(x, 0.f) + __logf(1.f + t) - 0.69314718f;
}

__device__ __forceinline__ unsigned short f2bf(float f) {
  unsigned int u = __float_as_uint(f);
  unsigned int r = (u + 0x7FFFu + ((u >> 16) & 1u)) >> 16;
  return (unsigned short)r;
}

// ===========================================================================
// precompute_C body (9 blocks, one d-slice each) -> CT[d][p][q pad 12]
// ===========================================================================
__device__ void precompute_body(
    int d, unsigned char* smem,
    const float* __restrict__ Ux_re, const float* __restrict__ Ux_im,
    const float* __restrict__ Uf_re, const float* __restrict__ Uf_im,
    const float* __restrict__ Vo_re, const float* __restrict__ Vo_im,
    float* __restrict__ CT) {
  float* G = (float*)smem;                // 2*729 f
  float* TL = (float*)(smem + 5840);      // 729 f
  float* cs9 = (float*)(smem + 8768);
  float* sn9 = (float*)(smem + 8816);
  const int t0 = threadIdx.x;

  if (t0 < 9) {
    float s, c;
    __sincosf(PI9 * (float)t0, &s, &c);
    cs9[t0] = c; sn9[t0] = s;
  }
  __syncthreads();

  for (int t = t0; t < 1458; t += 256) {
    const int which = t / 729, idx = t % 729;
    const int p = idx / 81, ab = idx % 81, a = ab / 9, b = ab % 9;
    const float* Ure = which ? Uf_re : Ux_re;
    const float* Uim = which ? Uf_im : Ux_im;
    float g = 0.f;
#pragma unroll
    for (int v = 0; v < 3; ++v) {
      const int uc = v + 2;
      float hre = 0.f, him = 0.f;
#pragma unroll
      for (int ui = 0; ui < 5; ++ui) {
        const int u = (ui + 7) % 9;
        const float re = Ure[p * 25 + ui * 5 + uc];
        const float im = Uim[p * 25 + ui * 5 + uc];
        const int k = (u * a) % 9;
        const float c = cs9[k], s = sn9[k];
        hre += re * c - im * s;
        him += re * s + im * c;
      }
      hre *= (1.f / 9.f); him *= (1.f / 9.f);
      if (v == 0) {
        g += hre;
      } else {
        const int k = (v * b) % 9;
        g += 2.f * (hre * cs9[k] - him * sn9[k]);
      }
    }
    G[which * 729 + p * 81 + ab] = g * (1.f / 9.f);
  }
  __syncthreads();

  for (int t = t0; t < 729; t += 256) {
    const int ab = t / 9, dd = t % 9, a = ab / 9, b = ab % 9;
    float acc = 0.f;
    for (int u = 0; u < 9; ++u)
      for (int v = 0; v < 5; ++v) {
        const int k = (u * a + v * b) % 9;
        acc += Vo_re[u * 45 + v * 9 + dd] * cs9[k]
             + Vo_im[u * 45 + v * 9 + dd] * sn9[k];
      }
    TL[ab * 9 + dd] = acc;
  }
  __syncthreads();

  if (t0 < 108) {
    const int p = t0 / 12, q = t0 % 12;
    float acc = 0.f;
    if (q < 9) {
      for (int ab = 0; ab < 81; ++ab)
        acc += G[p * 81 + ab] * G[729 + q * 81 + ab] * TL[ab * 9 + d];
    }
    CT[(d * 9 + p) * 12 + q] = acc;
  }
}

// ===========================================================================
// MLP body (4 reps = 256 edges / block); output w48b bf16 padded [e][16][4]
// ===========================================================================
__device__ void mlp_body(
    int mblk, unsigned char* smem, const float* __restrict__ win,
    const float* __restrict__ W1, const float* __restrict__ W2,
    const float* __restrict__ W3, const float* __restrict__ a_w,
    const float* __restrict__ den, unsigned short* __restrict__ w48b) {
  float* W1s = (float*)smem;                              // 2048 B
  unsigned short* W2T = (unsigned short*)(smem + 2048);   // 8192 B
  unsigned short* W3T = (unsigned short*)(smem + 10240);  // 6144 B
  unsigned short* H1 = (unsigned short*)(smem + 16384);   // 8192 B
  unsigned short* H2 = (unsigned short*)(smem + 24576);   // 8192 B
  const int t = threadIdx.x;

  const float invden = 1.f / den[0];
  const float sc0 = a_w[0] * invden, sc1 = a_w[10] * invden, sc2 = a_w[22] * invden;
  const float rs8 = 0.35355339059327373f;

  if (t < 128) {
    float4 v = ((const float4*)W1)[t];
    v.x *= rs8; v.y *= rs8; v.z *= rs8; v.w *= rs8;
    ((float4*)W1s)[t] = v;
  }
  for (int i = t; i < 4096; i += 256) {
    const int k = i >> 6, j = i & 63;
    W2T[j * 64 + ((((k >> 3) ^ (j & 7)) << 3)) + (k & 7)] = f2bf(W2[i] * 0.125f);
  }
  for (int i = t; i < 3072; i += 256) {
    const int k = i / 48, j = i % 48;
    const int jm = j % 3;
    const float s = (jm == 0) ? sc0 : ((jm == 1) ? sc1 : sc2);
    W3T[j * 64 + ((((k >> 3) ^ (j & 7)) << 3)) + (k & 7)] = f2bf(W3[i] * 0.125f * s);
  }
  __syncthreads();

  const int w = t >> 6, l = t & 63;
  const int er = l & 15, g = l >> 4;
  unsigned short* h1p = H1 + w * 1024;
  unsigned short* h2p = H2 + w * 1024;

#pragma unroll 1
  for (int rep = 0; rep < 4; ++rep) {
    const int e = mblk * 256 + rep * 64 + w * 16 + er;

    float in8[8];
    {
      const float4 A = *(const float4*)(win + (size_t)e * 8);
      const float4 B = *(const float4*)(win + (size_t)e * 8 + 4);
      in8[0] = A.x; in8[1] = A.y; in8[2] = A.z; in8[3] = A.w;
      in8[4] = B.x; in8[5] = B.y; in8[6] = B.z; in8[7] = B.w;
    }
    float h[16];
#pragma unroll
    for (int c = 0; c < 16; ++c) h[c] = 0.f;
#pragma unroll
    for (int k = 0; k < 8; ++k) {
      const float* wr = &W1s[k * 64 + g * 16];
      const float4 w0 = *(const float4*)wr;
      const float4 w1 = *(const float4*)(wr + 4);
      const float4 w2 = *(const float4*)(wr + 8);
      const float4 w3 = *(const float4*)(wr + 12);
      const float ik = in8[k];
      h[0]  = fmaf(ik, w0.x, h[0]);  h[1]  = fmaf(ik, w0.y, h[1]);
      h[2]  = fmaf(ik, w0.z, h[2]);  h[3]  = fmaf(ik, w0.w, h[3]);
      h[4]  = fmaf(ik, w1.x, h[4]);  h[5]  = fmaf(ik, w1.y, h[5]);
      h[6]  = fmaf(ik, w1.z, h[6]);  h[7]  = fmaf(ik, w1.w, h[7]);
      h[8]  = fmaf(ik, w2.x, h[8]);  h[9]  = fmaf(ik, w2.y, h[9]);
      h[10] = fmaf(ik, w2.z, h[10]); h[11] = fmaf(ik, w2.w, h[11]);
      h[12] = fmaf(ik, w3.x, h[12]); h[13] = fmaf(ik, w3.y, h[13]);
      h[14] = fmaf(ik, w3.z, h[14]); h[15] = fmaf(ik, w3.w, h[15]);
    }
    us8 pk0, pk1;
#pragma unroll
    for (int jj = 0; jj < 8; ++jj) pk0[jj] = f2bf(ssp_f(h[jj]));
#pragma unroll
    for (int jj = 0; jj < 8; ++jj) pk1[jj] = f2bf(ssp_f(h[8 + jj]));
    *(us8*)&h1p[er * 64 + (((2 * g) ^ (er & 7)) << 3)] = pk0;
    *(us8*)&h1p[er * 64 + (((2 * g + 1) ^ (er & 7)) << 3)] = pk1;
    __builtin_amdgcn_wave_barrier();

    const us8 a0 = *(const us8*)&h1p[er * 64 + ((g ^ (er & 7)) << 3)];
    const us8 a1 = *(const us8*)&h1p[er * 64 + (((g + 4) ^ (er & 7)) << 3)];
    float hh[16];
#pragma unroll
    for (int nt = 0; nt < 4; ++nt) {
      const int j = nt * 16 + er;
      const us8 b0 = *(const us8*)&W2T[j * 64 + ((g ^ (j & 7)) << 3)];
      const us8 b1 = *(const us8*)&W2T[j * 64 + (((g + 4) ^ (j & 7)) << 3)];
      f32x4 acc = {0.f, 0.f, 0.f, 0.f};
      acc = __builtin_amdgcn_mfma_f32_16x16x32_bf16(
          __builtin_bit_cast(bf16x8, a0), __builtin_bit_cast(bf16x8, b0), acc, 0, 0, 0);
      acc = __builtin_amdgcn_mfma_f32_16x16x32_bf16(
          __builtin_bit_cast(bf16x8, a1), __builtin_bit_cast(bf16x8, b1), acc, 0, 0, 0);
#pragma unroll
      for (int r = 0; r < 4; ++r) hh[nt * 4 + r] = ssp_f(acc[r]);
    }
#pragma unroll
    for (int nt = 0; nt < 4; ++nt)
#pragma unroll
      for (int r = 0; r < 4; ++r) {
        const int e2 = g * 4 + r;
        const int k2 = nt * 16 + er;
        h2p[e2 * 64 + ((((k2 >> 3) ^ (e2 & 7)) << 3)) + (k2 & 7)] = f2bf(hh[nt * 4 + r]);
      }
    __builtin_amdgcn_wave_barrier();

    const us8 c0 = *(const us8*)&h2p[er * 64 + ((g ^ (er & 7)) << 3)];
    const us8 c1 = *(const us8*)&h2p[er * 64 + (((g + 4) ^ (er & 7)) << 3)];
    const int ebase = mblk * 256 + rep * 64 + w * 16 + g * 4;
#pragma unroll
    for (int nt = 0; nt < 3; ++nt) {
      const int o = nt * 16 + er;
      const int om = o / 3, ol = o - om * 3;
      const us8 b0 = *(const us8*)&W3T[o * 64 + ((g ^ (o & 7)) << 3)];
      const us8 b1 = *(const us8*)&W3T[o * 64 + (((g + 4) ^ (o & 7)) << 3)];
      f32x4 acc = {0.f, 0.f, 0.f, 0.f};
      acc = __builtin_amdgcn_mfma_f32_16x16x32_bf16(
          __builtin_bit_cast(bf16x8, c0), __builtin_bit_cast(bf16x8, b0), acc, 0, 0, 0);
      acc = __builtin_amdgcn_mfma_f32_16x16x32_bf16(
          __builtin_bit_cast(bf16x8, c1), __builtin_bit_cast(bf16x8, b1), acc, 0, 0, 0);
#pragma unroll
      for (int r = 0; r < 4; ++r)
        w48b[(size_t)(ebase + r) * 64 + om * 4 + ol] = f2bf(acc[r]);
    }
    __builtin_amdgcn_wave_barrier();
  }
}

// ===========================================================================
// prep: [0,nMlp) MLP | [+nScat) scatter (packed int2 {e,src}) | [+9) CT
// ===========================================================================
__global__ __launch_bounds__(256) void prep_kernel(
    const float* __restrict__ win, const float* __restrict__ W1,
    const float* __restrict__ W2, const float* __restrict__ W3,
    const float* __restrict__ a_w, const float* __restrict__ den,
    unsigned short* __restrict__ w48b,
    const int* __restrict__ dst, const int* __restrict__ src, int E,
    int* __restrict__ cnt, int2* __restrict__ slots2,
    const float* __restrict__ Ux_re, const float* __restrict__ Ux_im,
    const float* __restrict__ Uf_re, const float* __restrict__ Uf_im,
    const float* __restrict__ Vo_re, const float* __restrict__ Vo_im,
    float* __restrict__ CT, int nMlp, int nScat) {
  __shared__ __align__(16) unsigned char smem[32768];
  const int bid = blockIdx.x;
  if (bid < nMlp) {
    mlp_body(bid, smem, win, W1, W2, W3, a_w, den, w48b);
  } else if (bid < nMlp + nScat) {
    const int e = (bid - nMlp) * 256 + threadIdx.x;
    if (e < E) {
      const int d = dst[e];
      const int pos = atomicAdd(&cnt[d], 1);
      if (pos < 96) slots2[(size_t)d * 96 + pos] = make_int2(e, src[e]);
    }
  } else {
    precompute_body(bid - nMlp - nScat, smem, Ux_re, Ux_im, Uf_re, Uf_im,
                    Vo_re, Vo_im, CT);
  }
}

// ===========================================================================
// Node kernel v10: wave-per-node, fused Me.
// Per 16-edge batch: Me[er, col=(d*9+p)] = f @ CB via 6 MFMAs (CB from CT,
// built once per wave); Me -> LDS (bf16, 24-short row stride, b128-aligned);
// then one message-MFMA per edge reading B rows from LDS.
// meT global buffer ELIMINATED.
// ===========================================================================
__global__ __launch_bounds__(256) void node_kernel(
    const float* __restrict__ x, const float* __restrict__ filt,
    const int* __restrict__ cnt, const int2* __restrict__ slots2,
    const unsigned short* __restrict__ w48b, const float* __restrict__ CT,
    float* __restrict__ out, int N) {
  __shared__ __align__(16) unsigned short meL[4][3456];  // [edge16][d9][24 shorts]
  const int t = threadIdx.x, w = t >> 6, l = t & 63;
  const int n16 = l & 15, g = l >> 4;
  const int Ld = (n16 == 0) ? 0 : ((n16 < 4) ? 1 : 2);
  const bool dok = n16 < 9;
  const int drow = dok ? n16 : 0;
  const int n = blockIdx.x * 4 + w;
  if (n >= N) return;

  // ---- per-lane constant: Me-MFMA B-frags (6 tiles) + (d,p) of my col/tile
  int dT0, pT0, dT1, pT1, dT2, pT2, dT3, pT3, dT4, pT4, dT5, pT5;
  bool ok0, ok1, ok2, ok3, ok4, ok5;
  bf16x8 Bme0, Bme1, Bme2, Bme3, Bme4, Bme5;
#define MKB(tt, Bv, dv, pv, okv)                                             \
  {                                                                          \
    const int col = tt * 16 + n16;                                           \
    okv = (col < 81);                                                        \
    dv = okv ? col / 9 : 0;                                                  \
    pv = okv ? col % 9 : 0;                                                  \
    bf16x8 bv;                                                               \
    _Pragma("unroll")                                                        \
    for (int j = 0; j < 8; ++j) bv[j] = (__bf16)0.f;                         \
    if (okv) {                                                               \
      const float* cp = CT + col * 12;                                       \
      if (g == 0) {                                                          \
        const float4 ca = *(const float4*)cp;                                \
        const float4 cb = *(const float4*)(cp + 4);                          \
        bv[0] = (__bf16)ca.x; bv[1] = (__bf16)ca.y;                          \
        bv[2] = (__bf16)ca.z; bv[3] = (__bf16)ca.w;                          \
        bv[4] = (__bf16)cb.x; bv[5] = (__bf16)cb.y;                          \
        bv[6] = (__bf16)cb.z; bv[7] = (__bf16)cb.w;                          \
      } else if (g == 1) {                                                   \
        bv[0] = (__bf16)cp[8];                                               \
      }                                                                      \
    }                                                                        \
    Bv = bv;                                                                 \
  }
  MKB(0, Bme0, dT0, pT0, ok0); MKB(1, Bme1, dT1, pT1, ok1);
  MKB(2, Bme2, dT2, pT2, ok2); MKB(3, Bme3, dT3, pT3, ok3);
  MKB(4, Bme4, dT4, pT4, ok4); MKB(5, Bme5, dT5, pT5, ok5);
#undef MKB

  int deg = cnt[n];
  if (deg > 96) deg = 96;
  const int2* sl2 = slots2 + (size_t)n * 96;
  unsigned short* mlw = &meL[w][0];

  f32x4 accm = {0.f, 0.f, 0.f, 0.f};

  const int nb = (deg + 15) >> 4;
  for (int b = 0; b < nb; ++b) {
    const int base = b * 16;
    const int degb = (deg - base < 16) ? (deg - base) : 16;

    // ---- batch edge list into lanes (er holds edge er) + Me A-frag
    int esx = 0, esy = 0;
    if (n16 < degb) {
      const int2 v = sl2[base + n16];
      esx = v.x; esy = v.y;
    }
    bf16x8 Af;
#pragma unroll
    for (int j = 0; j < 8; ++j) Af[j] = (__bf16)0.f;
    if (n16 < degb) {
      const float* fp = filt + (size_t)esx * 9;
      if (g == 0) {
        const float4 fa = *(const float4*)fp;
        const float4 fb = *(const float4*)(fp + 4);
        Af[0] = (__bf16)fa.x; Af[1] = (__bf16)fa.y;
        Af[2] = (__bf16)fa.z; Af[3] = (__bf16)fa.w;
        Af[4] = (__bf16)fb.x; Af[5] = (__bf16)fb.y;
        Af[6] = (__bf16)fb.z; Af[7] = (__bf16)fb.w;
      } else if (g == 1) {
        Af[0] = (__bf16)fp[8];
      }
    }

    // ---- 6 Me-MFMAs, store to LDS (row er'=g*4+r, [d][p])
#define MEMFMA(Bv, dv, pv, okv)                                              \
    {                                                                        \
      f32x4 a6 = {0.f, 0.f, 0.f, 0.f};                                       \
      a6 = __builtin_amdgcn_mfma_f32_16x16x32_bf16(Af, Bv, a6, 0, 0, 0);     \
      if (okv) {                                                             \
        _Pragma("unroll")                                                    \
        for (int r = 0; r < 4; ++r)                                          \
          mlw[(g * 4 + r) * 216 + dv * 24 + pv] = f2bf(a6[r]);               \
      }                                                                      \
    }
    MEMFMA(Bme0, dT0, pT0, ok0); MEMFMA(Bme1, dT1, pT1, ok1);
    MEMFMA(Bme2, dT2, pT2, ok2); MEMFMA(Bme3, dT3, pT3, ok3);
    MEMFMA(Bme4, dT4, pT4, ok4); MEMFMA(Bme5, dT5, pT5, ok5);
#undef MEMFMA
    __builtin_amdgcn_wave_barrier();

    // ---- message loop over this batch
    for (int il = 0; il < degb; ++il) {
      const int e = __builtin_amdgcn_readlane(esx, il);
      const int s = __builtin_amdgcn_readlane(esy, il);

      const float* xr = x + (size_t)s * 144 + n16 * 9;
      const float4 xa = *(const float4*)xr;
      const float4 xb = *(const float4*)(xr + 4);
      const float x8v = xr[8];

      const uint2 wv = *(const uint2*)(w48b + (size_t)e * 64 + n16 * 4);
      const float w0 = __uint_as_float(wv.x << 16);
      const float w1 = __uint_as_float(wv.x & 0xffff0000u);
      const float w2 = __uint_as_float(wv.y << 16);

      const unsigned short* mr = mlw + il * 216 + drow * 24;
      const u32x4 mdv = *(const u32x4*)mr;
      const unsigned int md0 = mdv[0], md1 = mdv[1], md2 = mdv[2], md3 = mdv[3];
      const unsigned int md4 = *(const unsigned int*)(mr + 8);

      bf16x8 A;
      unsigned int B0, B1, B2, B3;
      if (g == 0) {
        A[0] = (__bf16)(xa.x * w0); A[1] = (__bf16)(xa.y * w0);
        A[2] = (__bf16)(xa.z * w0); A[3] = (__bf16)(xa.w * w0);
        A[4] = (__bf16)(xb.x * w0); A[5] = (__bf16)(xb.y * w0);
        A[6] = (__bf16)(xb.z * w0); A[7] = (__bf16)(xb.w * w0);
        const bool s0 = (Ld == 0);
        B0 = s0 ? md0 : 0u; B1 = s0 ? md1 : 0u;
        B2 = s0 ? md2 : 0u; B3 = s0 ? md3 : 0u;
      } else if (g == 1) {
        A[0] = (__bf16)(x8v * w0);  A[1] = (__bf16)(xa.x * w1);
        A[2] = (__bf16)(xa.y * w1); A[3] = (__bf16)(xa.z * w1);
        A[4] = (__bf16)(xa.w * w1); A[5] = (__bf16)(xb.x * w1);
        A[6] = (__bf16)(xb.y * w1); A[7] = (__bf16)(xb.z * w1);
        const bool s0 = (Ld == 0), s1 = (Ld == 1);
        B0 = (s0 ? (md4 & 0xffffu) : 0u) | (s1 ? (md0 << 16) : 0u);
        B1 = s1 ? ((md0 >> 16) | (md1 << 16)) : 0u;
        B2 = s1 ? ((md1 >> 16) | (md2 << 16)) : 0u;
        B3 = s1 ? ((md2 >> 16) | (md3 << 16)) : 0u;
      } else if (g == 2) {
        A[0] = (__bf16)(xb.w * w1); A[1] = (__bf16)(x8v * w1);
        A[2] = (__bf16)(xa.x * w2); A[3] = (__bf16)(xa.y * w2);
        A[4] = (__bf16)(xa.z * w2); A[5] = (__bf16)(xa.w * w2);
        A[6] = (__bf16)(xb.x * w2); A[7] = (__bf16)(xb.y * w2);
        const bool s1 = (Ld == 1), s2 = (Ld == 2);
        B0 = s1 ? ((md3 >> 16) | (md4 << 16)) : 0u;
        B1 = s2 ? md0 : 0u; B2 = s2 ? md1 : 0u; B3 = s2 ? md2 : 0u;
      } else {
        A[0] = (__bf16)(xb.z * w2); A[1] = (__bf16)(xb.w * w2);
        A[2] = (__bf16)(x8v * w2);
        A[3] = (__bf16)0.f; A[4] = (__bf16)0.f; A[5] = (__bf16)0.f;
        A[6] = (__bf16)0.f; A[7] = (__bf16)0.f;
        const bool s2 = (Ld == 2);
        B0 = s2 ? md3 : 0u;
        B1 = s2 ? (md4 & 0xffffu) : 0u;
        B2 = 0u; B3 = 0u;
      }
      u32x4 bv = {B0, B1, B2, B3};
      accm = __builtin_amdgcn_mfma_f32_16x16x32_bf16(
          A, __builtin_bit_cast(bf16x8, bv), accm, 0, 0, 0);
    }
    __builtin_amdgcn_wave_barrier();   // before next batch overwrites LDS
  }

  // ---- write out: C layout col d = lane&15, row m = g*4 + r
  if (dok) {
    float* op = out + (size_t)n * 144 + (g * 4) * 9 + n16;
    op[0]  = accm[0];
    op[9]  = accm[1];
    op[18] = accm[2];
    op[27] = accm[3];
  }
}

// ---------------------------------------------------------------------------
extern "C" void kernel_launch(void* const* d_in, const int* in_sizes, int n_in,
                              void* d_out, int out_size, void* d_ws, size_t ws_size,
                              hipStream_t stream) {
  const float* x      = (const float*)d_in[0];
  const float* filt   = (const float*)d_in[1];
  const float* win    = (const float*)d_in[2];
  const int*   eidx   = (const int*)d_in[3];
  const float* Ux_re  = (const float*)d_in[4];
  const float* Ux_im  = (const float*)d_in[5];
  const float* Uf_re  = (const float*)d_in[6];
  const float* Uf_im  = (const float*)d_in[7];
  const float* Vo_re  = (const float*)d_in[8];
  const float* Vo_im  = (const float*)d_in[9];
  const float* W1     = (const float*)d_in[10];
  const float* W2     = (const float*)d_in[11];
  const float* W3     = (const float*)d_in[12];
  const float* a_w    = (const float*)d_in[13];
  const float* den    = (const float*)d_in[14];
  float* out = (float*)d_out;

  const int N = in_sizes[0] / 144;          // 10000
  const int E = in_sizes[3] / 2;            // 160000
  const int* dst = eidx;
  const int* src = eidx + E;

  char* wsb = (char*)d_ws;
  const size_t off_cnt  = 8192;
  const size_t off_slot = off_cnt + 40960;
  const size_t off_w48  = off_slot + (size_t)N * 96 * 8;

  float*          CT    = (float*)wsb;
  int*            cnt   = (int*)(wsb + off_cnt);
  int2*           slot2 = (int2*)(wsb + off_slot);
  unsigned short* w48b  = (unsigned short*)(wsb + off_w48);  // E*64 shorts

  const int nMlp  = E / 256;                // 625
  const int nScat = (E + 255) / 256;        // 625

  hipMemsetAsync(cnt, 0, (size_t)N * sizeof(int), stream);
  prep_kernel<<<nMlp + nScat + 9, 256, 0, stream>>>(
      win, W1, W2, W3, a_w, den, w48b,
      dst, src, E, cnt, slot2,
      Ux_re, Ux_im, Uf_re, Uf_im, Vo_re, Vo_im, CT, nMlp, nScat);
  node_kernel<<<(N + 3) / 4, 256, 0, stream>>>(
      x, filt, cnt, slot2, w48b, CT, out, N);
}